// Round 5
// baseline (6123.151 us; speedup 1.0000x reference)
//
#include <hip/hip_runtime.h>
#include <hip/hip_bf16.h>
#include <math.h>

#define NN 100000
#define NE 1600000
#define NR 8
#define DD 64
#define DDR 64

// ---- order-preserving float<->uint encoding for atomicMax (0 == very-negative floor) ----
__device__ __forceinline__ unsigned enc_f(float f) {
    unsigned u = __float_as_uint(f);
    return (u & 0x80000000u) ? ~u : (u | 0x80000000u);
}
__device__ __forceinline__ float dec_f(unsigned u) {
    return (u & 0x80000000u) ? __uint_as_float(u & 0x7FFFFFFFu) : __uint_as_float(~u);
}

__device__ __forceinline__ unsigned f2bf(float x) {
    __hip_bfloat16 h = __float2bfloat16(x);   // round-to-nearest
    return (unsigned)*reinterpret_cast<unsigned short*>(&h);
}
__device__ __forceinline__ unsigned pack2bf(float a, float b) {
    return f2bf(a) | (f2bf(b) << 16);
}
__device__ __forceinline__ float bflo(unsigned u) { return __uint_as_float(u << 16); }
__device__ __forceinline__ float bfhi(unsigned u) { return __uint_as_float(u & 0xFFFF0000u); }

// ---- Kernel P: proj[r][n][:] = emb[n] @ W_R[r], tiled GEMM, bf16 output ----
// grid (ceil(N/64), R), block 256.
// __launch_bounds__(256,4): LDS (34KB) already caps at 4 blocks/CU = 4 waves/EU,
// so let the register allocator use 128 VGPRs — without this the compiler caps
// at 64 VGPRs and SPILLS the 16-float accumulator to scratch (measured: 15 GB
// of HBM traffic instead of ~0.5 GB, k_proj 4900us at VALUBusy 1.5%).
__global__ void __launch_bounds__(256, 4)
k_proj(const float* __restrict__ emb, const float* __restrict__ WR,
       unsigned* __restrict__ proj)   // proj as packed bf16x2
{
    __shared__ float a_t[64][68];
    __shared__ float w_t[64][68];
    int n0 = blockIdx.x * 64;
    int r = blockIdx.y;
    int t = threadIdx.x;
#pragma unroll
    for (int i = 0; i < 4; ++i) {
        int f = t + i * 256;            // float4 slot 0..1023
        int row = f >> 4;
        int col = (f & 15) * 4;
        float4 v = make_float4(0.f, 0.f, 0.f, 0.f);
        if (n0 + row < NN) v = *(const float4*)(emb + (long)(n0 + row) * DD + col);
        a_t[row][col] = v.x; a_t[row][col + 1] = v.y; a_t[row][col + 2] = v.z; a_t[row][col + 3] = v.w;
        float4 w = *(const float4*)(WR + (long)r * (DD * DDR) + row * DDR + col);
        w_t[row][col] = w.x; w_t[row][col + 1] = w.y; w_t[row][col + 2] = w.z; w_t[row][col + 3] = w.w;
    }
    __syncthreads();
    int tx = t & 15, ty = t >> 4;
    float acc[4][4];
#pragma unroll
    for (int ii = 0; ii < 4; ++ii)
#pragma unroll
        for (int jj = 0; jj < 4; ++jj) acc[ii][jj] = 0.f;

    for (int k = 0; k < 64; k += 4) {
        float4 wv0 = *(const float4*)&w_t[k + 0][tx * 4];
        float4 wv1 = *(const float4*)&w_t[k + 1][tx * 4];
        float4 wv2 = *(const float4*)&w_t[k + 2][tx * 4];
        float4 wv3 = *(const float4*)&w_t[k + 3][tx * 4];
#pragma unroll
        for (int ii = 0; ii < 4; ++ii) {
            float4 av = *(const float4*)&a_t[ty * 4 + ii][k];
            acc[ii][0] = fmaf(av.x, wv0.x, acc[ii][0]); acc[ii][1] = fmaf(av.x, wv0.y, acc[ii][1]);
            acc[ii][2] = fmaf(av.x, wv0.z, acc[ii][2]); acc[ii][3] = fmaf(av.x, wv0.w, acc[ii][3]);
            acc[ii][0] = fmaf(av.y, wv1.x, acc[ii][0]); acc[ii][1] = fmaf(av.y, wv1.y, acc[ii][1]);
            acc[ii][2] = fmaf(av.y, wv1.z, acc[ii][2]); acc[ii][3] = fmaf(av.y, wv1.w, acc[ii][3]);
            acc[ii][0] = fmaf(av.z, wv2.x, acc[ii][0]); acc[ii][1] = fmaf(av.z, wv2.y, acc[ii][1]);
            acc[ii][2] = fmaf(av.z, wv2.z, acc[ii][2]); acc[ii][3] = fmaf(av.z, wv2.w, acc[ii][3]);
            acc[ii][0] = fmaf(av.w, wv3.x, acc[ii][0]); acc[ii][1] = fmaf(av.w, wv3.y, acc[ii][1]);
            acc[ii][2] = fmaf(av.w, wv3.z, acc[ii][2]); acc[ii][3] = fmaf(av.w, wv3.w, acc[ii][3]);
        }
    }
#pragma unroll
    for (int ii = 0; ii < 4; ++ii) {
        int n = n0 + ty * 4 + ii;
        if (n < NN) {
            uint2 o;
            o.x = pack2bf(acc[ii][0], acc[ii][1]);
            o.y = pack2bf(acc[ii][2], acc[ii][3]);
            // [r][n][dr] packed-pair layout: row stride 32 uints = 128B, contiguous per block
            *(uint2*)(proj + ((long)r * NN + n) * 32 + tx * 2) = o;
        }
    }
}

// ---- Kernel A': gather attention logits + segment max (16 lanes/edge) ----
__global__ void k_attg(const unsigned* __restrict__ proj, const float* __restrict__ rel,
                       const int* __restrict__ src, const int* __restrict__ dst,
                       const int* __restrict__ et,
                       float* __restrict__ att, unsigned* __restrict__ mkey)
{
    long tid = (long)blockIdx.x * blockDim.x + threadIdx.x;
    int e = (int)(tid >> 4);
    int j = threadIdx.x & 15;
    if (e >= NE) return;
    int s = src[e], d = dst[e], r = et[e];
    uint2 tv = *(const uint2*)(proj + ((long)r * NN + s) * 32 + j * 2);
    uint2 hv = *(const uint2*)(proj + ((long)r * NN + d) * 32 + j * 2);
    float4 rv = *(const float4*)(rel + r * DDR + j * 4);
    float sum = bflo(tv.x) * tanhf(bflo(hv.x) + rv.x)
              + bfhi(tv.x) * tanhf(bfhi(hv.x) + rv.y)
              + bflo(tv.y) * tanhf(bflo(hv.y) + rv.z)
              + bfhi(tv.y) * tanhf(bfhi(hv.y) + rv.w);
#pragma unroll
    for (int off = 8; off; off >>= 1) sum += __shfl_xor(sum, off);
    if (j == 0) {
        att[e] = sum;
        atomicMax(mkey + d, enc_f(sum));
    }
}

// ---- Fallback kernel (old direct per-edge matvec) if ws too small ----
__global__ void k_att(const float* __restrict__ emb, const float* __restrict__ rel,
                      const float* __restrict__ WR, const int* __restrict__ src,
                      const int* __restrict__ dst, const int* __restrict__ et,
                      float* __restrict__ att, unsigned* __restrict__ mkey)
{
    int e = (int)((blockIdx.x * blockDim.x + threadIdx.x) >> 6);
    int lane = threadIdx.x & 63;
    if (e >= NE) return;
    int s = src[e], d = dst[e], r = et[e];
    const float* __restrict__ es = emb + (long)s * DD;
    const float* __restrict__ eh = emb + (long)d * DD;
    const float* __restrict__ w  = WR + r * (DD * DDR) + lane;
    float at = 0.f, ah = 0.f;
#pragma unroll 8
    for (int dd = 0; dd < DD; ++dd) {
        float ws = w[dd * DDR];
        at = fmaf(es[dd], ws, at);
        ah = fmaf(eh[dd], ws, ah);
    }
    float term = at * tanhf(ah + rel[r * DDR + lane]);
#pragma unroll
    for (int off = 32; off; off >>= 1) term += __shfl_xor(term, off);
    if (lane == 0) {
        att[e] = term;
        atomicMax(mkey + d, enc_f(term));
    }
}

// ---- Kernel B: ex = exp(att - m[dst]); segment sum ----
__global__ void k_expsum(const int* __restrict__ dst, float* __restrict__ att,
                         const unsigned* __restrict__ mkey, float* __restrict__ ssum)
{
    int e = blockIdx.x * blockDim.x + threadIdx.x;
    if (e >= NE) return;
    int d = dst[e];
    float ex = expf(att[e] - dec_f(mkey[d]));
    att[e] = ex;
    atomicAdd(ssum + d, ex);
}

// ---- Kernel D: layer-0 aggregation; finalizes a[e] = ex/ssum ----
__global__ void k_agg0(const float* __restrict__ emb, const int* __restrict__ src,
                       const int* __restrict__ dst, float* __restrict__ att,
                       const float* __restrict__ ssum, float* __restrict__ Nh)
{
    int e = (int)((blockIdx.x * blockDim.x + threadIdx.x) >> 6);
    int lane = threadIdx.x & 63;
    if (e >= NE) return;
    int s = src[e], d = dst[e];
    float a = att[e] / ssum[d];
    if (lane == 0) att[e] = a;
    float v = emb[(long)s * DD + lane] * a;
    atomicAdd(Nh + (long)d * DD + lane, v);
}

// ---- Kernel E: layer-0 node update; writes ego (cols 0..64) and h1 (cols 64..96) ----
__global__ void k_node0(const float* __restrict__ emb, const float* __restrict__ Nh,
                        const float* __restrict__ W1, const float* __restrict__ b1,
                        const float* __restrict__ W2, const float* __restrict__ b2,
                        float* __restrict__ out)
{
    int node = (int)((blockIdx.x * blockDim.x + threadIdx.x) >> 6);
    int lane = threadIdx.x & 63;
    if (node >= NN) return;
    const float* __restrict__ x  = emb + (long)node * DD;
    const float* __restrict__ nh = Nh + (long)node * DD;
    int j = lane & 31;
    const float* __restrict__ W = (lane < 32) ? (W1 + j * DD) : (W2 + j * DD);
    float acc = 0.f;
#pragma unroll 8
    for (int dd = 0; dd < DD; ++dd) {
        float xv = x[dd], nv = nh[dd];
        float v = (lane < 32) ? (xv + nv) : (xv * nv);
        acc = fmaf(v, W[dd], acc);
    }
    acc += (lane < 32) ? b1[j] : b2[j];
    acc = (acc >= 0.f) ? acc : 0.01f * acc;
    float other = __shfl_down(acc, 32);
    float h = acc + other;
    float ss = h * h;
#pragma unroll
    for (int off = 16; off; off >>= 1) ss += __shfl_xor(ss, off);
    float nrm = sqrtf(ss);
    float hn = h / fmaxf(nrm, 1e-12f);
    out[(long)node * 112 + lane] = x[lane];
    if (lane < 32) out[(long)node * 112 + 64 + j] = hn;
}

// ---- Kernel F: layer-1 aggregation ----
__global__ void k_agg1(const float* __restrict__ out, const int* __restrict__ src,
                       const int* __restrict__ dst, const float* __restrict__ att,
                       float* __restrict__ Nh1)
{
    int idx = blockIdx.x * blockDim.x + threadIdx.x;
    int e = idx >> 5;
    int j = idx & 31;
    if (e >= NE) return;
    int s = src[e], d = dst[e];
    float a = att[e];
    float v = out[(long)s * 112 + 64 + j] * a;
    atomicAdd(Nh1 + (long)d * 32 + j, v);
}

// ---- Kernel G: layer-1 node update; writes h2 (cols 96..112) ----
__global__ void k_node1(const float* __restrict__ outbuf, const float* __restrict__ Nh1,
                        const float* __restrict__ W1, const float* __restrict__ b1,
                        const float* __restrict__ W2, const float* __restrict__ b2,
                        float* __restrict__ out)
{
    int t = blockIdx.x * blockDim.x + threadIdx.x;
    int node = t >> 5;
    int lane = t & 31;
    if (node >= NN) return;
    const float* __restrict__ x  = outbuf + (long)node * 112 + 64;
    const float* __restrict__ nh = Nh1 + (long)node * 32;
    int j = lane & 15;
    const float* __restrict__ W = (lane < 16) ? (W1 + j * 32) : (W2 + j * 32);
    float acc = 0.f;
#pragma unroll 8
    for (int dd = 0; dd < 32; ++dd) {
        float xv = x[dd], nv = nh[dd];
        float v = (lane < 16) ? (xv + nv) : (xv * nv);
        acc = fmaf(v, W[dd], acc);
    }
    acc += (lane < 16) ? b1[j] : b2[j];
    acc = (acc >= 0.f) ? acc : 0.01f * acc;
    float other = __shfl_down(acc, 16, 32);
    float h = acc + other;
    float ss = h * h;
#pragma unroll
    for (int off = 8; off; off >>= 1) ss += __shfl_xor(ss, off);
    float nrm = sqrtf(ss);
    float hn = h / fmaxf(nrm, 1e-12f);
    if (lane < 16) out[(long)node * 112 + 96 + j] = hn;
}

extern "C" void kernel_launch(void* const* d_in, const int* in_sizes, int n_in,
                              void* d_out, int out_size, void* d_ws, size_t ws_size,
                              hipStream_t stream) {
    const float* emb  = (const float*)d_in[0];
    const float* rel  = (const float*)d_in[1];
    const float* WR   = (const float*)d_in[2];
    const float* W1_0 = (const float*)d_in[3];
    const float* b1_0 = (const float*)d_in[4];
    const float* W2_0 = (const float*)d_in[5];
    const float* b2_0 = (const float*)d_in[6];
    const float* W1_1 = (const float*)d_in[7];
    const float* b1_1 = (const float*)d_in[8];
    const float* W2_1 = (const float*)d_in[9];
    const float* b2_1 = (const float*)d_in[10];
    const int*   src  = (const int*)d_in[11];
    const int*   dst  = (const int*)d_in[12];
    const int*   et   = (const int*)d_in[13];
    float* out = (float*)d_out;

    // workspace layout (floats): [mkey N][ssum N][Nh0 64N][Nh1 32N][att E][proj bf16x2 N*R*32 uints]
    unsigned* mkey = (unsigned*)d_ws;
    float* ssum = (float*)d_ws + NN;
    float* Nh0  = (float*)d_ws + 2 * NN;
    float* Nh1  = (float*)d_ws + (2 + DD) * NN;
    float* att  = (float*)d_ws + (2 + DD + 32) * NN;
    unsigned* proj = (unsigned*)(att + NE);

    size_t need = (size_t)(2 + DD + 32) * NN * 4 + (size_t)NE * 4
                + (size_t)NN * NR * DDR * 2;

    // zero mkey/ssum/Nh0/Nh1 (att & proj fully overwritten)
    hipMemsetAsync(d_ws, 0, (size_t)(2 + DD + 32) * NN * sizeof(float), stream);

    if (ws_size >= need) {
        k_proj<<<dim3((NN + 63) / 64, NR), dim3(256), 0, stream>>>(emb, WR, proj);
        k_attg<<<dim3((int)(((long)NE * 16 + 255) / 256)), dim3(256), 0, stream>>>(
            proj, rel, src, dst, et, att, mkey);
    } else {
        k_att<<<dim3((int)(((long)NE * 64 + 255) / 256)), dim3(256), 0, stream>>>(
            emb, rel, WR, src, dst, et, att, mkey);
    }
    k_expsum<<<dim3((NE + 255) / 256), dim3(256), 0, stream>>>(dst, att, mkey, ssum);
    k_agg0<<<dim3((int)(((long)NE * 64 + 255) / 256)), dim3(256), 0, stream>>>(
        emb, src, dst, att, ssum, Nh0);
    k_node0<<<dim3((int)(((long)NN * 64 + 255) / 256)), dim3(256), 0, stream>>>(
        emb, Nh0, W1_0, b1_0, W2_0, b2_0, out);
    k_agg1<<<dim3((int)(((long)NE * 32 + 255) / 256)), dim3(256), 0, stream>>>(
        out, src, dst, att, Nh1);
    k_node1<<<dim3((int)(((long)NN * 32 + 255) / 256)), dim3(256), 0, stream>>>(
        out, Nh1, W1_1, b1_1, W2_1, b2_1, out);
}

// Round 6
// 2452.575 us; speedup vs baseline: 2.4966x; 2.4966x over previous
//
#include <hip/hip_runtime.h>
#include <hip/hip_bf16.h>
#include <math.h>

#define NN 100000
#define NE 1600000
#define NR 8
#define DD 64
#define DDR 64

// ---- order-preserving float<->uint encoding for atomicMax (0 == very-negative floor) ----
__device__ __forceinline__ unsigned enc_f(float f) {
    unsigned u = __float_as_uint(f);
    return (u & 0x80000000u) ? ~u : (u | 0x80000000u);
}
__device__ __forceinline__ float dec_f(unsigned u) {
    return (u & 0x80000000u) ? __uint_as_float(u & 0x7FFFFFFFu) : __uint_as_float(~u);
}

__device__ __forceinline__ float bflo(unsigned u) { return __uint_as_float(u << 16); }
__device__ __forceinline__ float bfhi(unsigned u) { return __uint_as_float(u & 0xFFFF0000u); }

// ---- Kernel P2: proj[r][n][k] = emb[n] @ W_R[r], W-in-registers matvec ----
// One wave per (16 nodes, 1 relation). Lane k holds W_R[r][:,k] in 64 VGPRs
// (coalesced load, reused 16x). x[d] is wave-uniform -> batched scalar loads.
// Output: 128B coalesced bf16 row per node. No LDS, no vector-cast tricks —
// every byte of traffic is auditable: emb 25.6MB in, proj 102MB out.
// (Replaces the LDS-tiled GEMM that moved an unexplainable 15 GB/dispatch.)
__global__ void k_proj2(const float* __restrict__ emb, const float* __restrict__ WR,
                        unsigned short* __restrict__ proj)
{
    int t = threadIdx.x;
    int wv = t >> 6;
    int lane = t & 63;
    int r = blockIdx.y;
    int nbase = blockIdx.x * 64 + wv * 16;
    const float* __restrict__ Wr = WR + (long)r * (DD * DDR) + lane;
    float w[DD];
#pragma unroll
    for (int d = 0; d < DD; ++d) w[d] = Wr[d * DDR];
    int nend = (nbase + 16 < NN) ? (nbase + 16) : NN;
    for (int n = nbase; n < nend; ++n) {
        const float* __restrict__ x = emb + (long)n * DD;   // wave-uniform row
        float acc = 0.f;
#pragma unroll
        for (int d = 0; d < DD; ++d) acc = fmaf(x[d], w[d], acc);
        __hip_bfloat16 h = __float2bfloat16(acc);
        proj[((long)r * NN + n) * DDR + lane] = *reinterpret_cast<unsigned short*>(&h);
    }
}

// ---- Kernel A': gather attention logits + segment max (16 lanes/edge) ----
__global__ void k_attg(const unsigned* __restrict__ proj, const float* __restrict__ rel,
                       const int* __restrict__ src, const int* __restrict__ dst,
                       const int* __restrict__ et,
                       float* __restrict__ att, unsigned* __restrict__ mkey)
{
    long tid = (long)blockIdx.x * blockDim.x + threadIdx.x;
    int e = (int)(tid >> 4);
    int j = threadIdx.x & 15;
    if (e >= NE) return;
    int s = src[e], d = dst[e], r = et[e];
    uint2 tv = *(const uint2*)(proj + ((long)r * NN + s) * 32 + j * 2);
    uint2 hv = *(const uint2*)(proj + ((long)r * NN + d) * 32 + j * 2);
    float4 rv = *(const float4*)(rel + r * DDR + j * 4);
    float sum = bflo(tv.x) * tanhf(bflo(hv.x) + rv.x)
              + bfhi(tv.x) * tanhf(bfhi(hv.x) + rv.y)
              + bflo(tv.y) * tanhf(bflo(hv.y) + rv.z)
              + bfhi(tv.y) * tanhf(bfhi(hv.y) + rv.w);
#pragma unroll
    for (int off = 8; off; off >>= 1) sum += __shfl_xor(sum, off);
    if (j == 0) {
        att[e] = sum;
        atomicMax(mkey + d, enc_f(sum));
    }
}

// ---- Fallback kernel (old direct per-edge matvec) if ws too small ----
__global__ void k_att(const float* __restrict__ emb, const float* __restrict__ rel,
                      const float* __restrict__ WR, const int* __restrict__ src,
                      const int* __restrict__ dst, const int* __restrict__ et,
                      float* __restrict__ att, unsigned* __restrict__ mkey)
{
    int e = (int)((blockIdx.x * blockDim.x + threadIdx.x) >> 6);
    int lane = threadIdx.x & 63;
    if (e >= NE) return;
    int s = src[e], d = dst[e], r = et[e];
    const float* __restrict__ es = emb + (long)s * DD;
    const float* __restrict__ eh = emb + (long)d * DD;
    const float* __restrict__ w  = WR + r * (DD * DDR) + lane;
    float at = 0.f, ah = 0.f;
#pragma unroll 8
    for (int dd = 0; dd < DD; ++dd) {
        float ws = w[dd * DDR];
        at = fmaf(es[dd], ws, at);
        ah = fmaf(eh[dd], ws, ah);
    }
    float term = at * tanhf(ah + rel[r * DDR + lane]);
#pragma unroll
    for (int off = 32; off; off >>= 1) term += __shfl_xor(term, off);
    if (lane == 0) {
        att[e] = term;
        atomicMax(mkey + d, enc_f(term));
    }
}

// ---- Kernel B: ex = exp(att - m[dst]); segment sum ----
__global__ void k_expsum(const int* __restrict__ dst, float* __restrict__ att,
                         const unsigned* __restrict__ mkey, float* __restrict__ ssum)
{
    int e = blockIdx.x * blockDim.x + threadIdx.x;
    if (e >= NE) return;
    int d = dst[e];
    float ex = expf(att[e] - dec_f(mkey[d]));
    att[e] = ex;
    atomicAdd(ssum + d, ex);
}

// ---- Kernel D: layer-0 aggregation; finalizes a[e] = ex/ssum ----
__global__ void k_agg0(const float* __restrict__ emb, const int* __restrict__ src,
                       const int* __restrict__ dst, float* __restrict__ att,
                       const float* __restrict__ ssum, float* __restrict__ Nh)
{
    int e = (int)((blockIdx.x * blockDim.x + threadIdx.x) >> 6);
    int lane = threadIdx.x & 63;
    if (e >= NE) return;
    int s = src[e], d = dst[e];
    float a = att[e] / ssum[d];
    if (lane == 0) att[e] = a;
    float v = emb[(long)s * DD + lane] * a;
    atomicAdd(Nh + (long)d * DD + lane, v);
}

// ---- Kernel E: layer-0 node update; writes ego (cols 0..64) and h1 (cols 64..96) ----
__global__ void k_node0(const float* __restrict__ emb, const float* __restrict__ Nh,
                        const float* __restrict__ W1, const float* __restrict__ b1,
                        const float* __restrict__ W2, const float* __restrict__ b2,
                        float* __restrict__ out)
{
    int node = (int)((blockIdx.x * blockDim.x + threadIdx.x) >> 6);
    int lane = threadIdx.x & 63;
    if (node >= NN) return;
    const float* __restrict__ x  = emb + (long)node * DD;
    const float* __restrict__ nh = Nh + (long)node * DD;
    int j = lane & 31;
    const float* __restrict__ W = (lane < 32) ? (W1 + j * DD) : (W2 + j * DD);
    float acc = 0.f;
#pragma unroll 8
    for (int dd = 0; dd < DD; ++dd) {
        float xv = x[dd], nv = nh[dd];
        float v = (lane < 32) ? (xv + nv) : (xv * nv);
        acc = fmaf(v, W[dd], acc);
    }
    acc += (lane < 32) ? b1[j] : b2[j];
    acc = (acc >= 0.f) ? acc : 0.01f * acc;
    float other = __shfl_down(acc, 32);
    float h = acc + other;
    float ss = h * h;
#pragma unroll
    for (int off = 16; off; off >>= 1) ss += __shfl_xor(ss, off);
    float nrm = sqrtf(ss);
    float hn = h / fmaxf(nrm, 1e-12f);
    out[(long)node * 112 + lane] = x[lane];
    if (lane < 32) out[(long)node * 112 + 64 + j] = hn;
}

// ---- Kernel F: layer-1 aggregation ----
__global__ void k_agg1(const float* __restrict__ out, const int* __restrict__ src,
                       const int* __restrict__ dst, const float* __restrict__ att,
                       float* __restrict__ Nh1)
{
    int idx = blockIdx.x * blockDim.x + threadIdx.x;
    int e = idx >> 5;
    int j = idx & 31;
    if (e >= NE) return;
    int s = src[e], d = dst[e];
    float a = att[e];
    float v = out[(long)s * 112 + 64 + j] * a;
    atomicAdd(Nh1 + (long)d * 32 + j, v);
}

// ---- Kernel G: layer-1 node update; writes h2 (cols 96..112) ----
__global__ void k_node1(const float* __restrict__ outbuf, const float* __restrict__ Nh1,
                        const float* __restrict__ W1, const float* __restrict__ b1,
                        const float* __restrict__ W2, const float* __restrict__ b2,
                        float* __restrict__ out)
{
    int t = blockIdx.x * blockDim.x + threadIdx.x;
    int node = t >> 5;
    int lane = t & 31;
    if (node >= NN) return;
    const float* __restrict__ x  = outbuf + (long)node * 112 + 64;
    const float* __restrict__ nh = Nh1 + (long)node * 32;
    int j = lane & 15;
    const float* __restrict__ W = (lane < 16) ? (W1 + j * 32) : (W2 + j * 32);
    float acc = 0.f;
#pragma unroll 8
    for (int dd = 0; dd < 32; ++dd) {
        float xv = x[dd], nv = nh[dd];
        float v = (lane < 16) ? (xv + nv) : (xv * nv);
        acc = fmaf(v, W[dd], acc);
    }
    acc += (lane < 16) ? b1[j] : b2[j];
    acc = (acc >= 0.f) ? acc : 0.01f * acc;
    float other = __shfl_down(acc, 16, 32);
    float h = acc + other;
    float ss = h * h;
#pragma unroll
    for (int off = 8; off; off >>= 1) ss += __shfl_xor(ss, off);
    float nrm = sqrtf(ss);
    float hn = h / fmaxf(nrm, 1e-12f);
    if (lane < 16) out[(long)node * 112 + 96 + j] = hn;
}

extern "C" void kernel_launch(void* const* d_in, const int* in_sizes, int n_in,
                              void* d_out, int out_size, void* d_ws, size_t ws_size,
                              hipStream_t stream) {
    const float* emb  = (const float*)d_in[0];
    const float* rel  = (const float*)d_in[1];
    const float* WR   = (const float*)d_in[2];
    const float* W1_0 = (const float*)d_in[3];
    const float* b1_0 = (const float*)d_in[4];
    const float* W2_0 = (const float*)d_in[5];
    const float* b2_0 = (const float*)d_in[6];
    const float* W1_1 = (const float*)d_in[7];
    const float* b1_1 = (const float*)d_in[8];
    const float* W2_1 = (const float*)d_in[9];
    const float* b2_1 = (const float*)d_in[10];
    const int*   src  = (const int*)d_in[11];
    const int*   dst  = (const int*)d_in[12];
    const int*   et   = (const int*)d_in[13];
    float* out = (float*)d_out;

    // workspace layout (floats): [mkey N][ssum N][Nh0 64N][Nh1 32N][att E][proj bf16 N*R*64]
    unsigned* mkey = (unsigned*)d_ws;
    float* ssum = (float*)d_ws + NN;
    float* Nh0  = (float*)d_ws + 2 * NN;
    float* Nh1  = (float*)d_ws + (2 + DD) * NN;
    float* att  = (float*)d_ws + (2 + DD + 32) * NN;
    unsigned* proj = (unsigned*)(att + NE);

    size_t need = (size_t)(2 + DD + 32) * NN * 4 + (size_t)NE * 4
                + (size_t)NN * NR * DDR * 2;

    // zero mkey/ssum/Nh0/Nh1 (att & proj fully overwritten)
    hipMemsetAsync(d_ws, 0, (size_t)(2 + DD + 32) * NN * sizeof(float), stream);

    if (ws_size >= need) {
        k_proj2<<<dim3((NN + 63) / 64, NR), dim3(256), 0, stream>>>(
            emb, WR, (unsigned short*)proj);
        k_attg<<<dim3((int)(((long)NE * 16 + 255) / 256)), dim3(256), 0, stream>>>(
            proj, rel, src, dst, et, att, mkey);
    } else {
        k_att<<<dim3((int)(((long)NE * 64 + 255) / 256)), dim3(256), 0, stream>>>(
            emb, rel, WR, src, dst, et, att, mkey);
    }
    k_expsum<<<dim3((NE + 255) / 256), dim3(256), 0, stream>>>(dst, att, mkey, ssum);
    k_agg0<<<dim3((int)(((long)NE * 64 + 255) / 256)), dim3(256), 0, stream>>>(
        emb, src, dst, att, ssum, Nh0);
    k_node0<<<dim3((int)(((long)NN * 64 + 255) / 256)), dim3(256), 0, stream>>>(
        emb, Nh0, W1_0, b1_0, W2_0, b2_0, out);
    k_agg1<<<dim3((int)(((long)NE * 32 + 255) / 256)), dim3(256), 0, stream>>>(
        out, src, dst, att, Nh1);
    k_node1<<<dim3((int)(((long)NN * 32 + 255) / 256)), dim3(256), 0, stream>>>(
        out, Nh1, W1_1, b1_1, W2_1, b2_1, out);
}

// Round 7
// 1501.219 us; speedup vs baseline: 4.0788x; 1.6337x over previous
//
#include <hip/hip_runtime.h>
#include <hip/hip_bf16.h>
#include <math.h>

#define NN 100000
#define NE 1600000
#define NR 8
#define DD 64
#define DDR 64

// ---- order-preserving float<->uint encoding for atomicMax (0 == very-negative floor) ----
__device__ __forceinline__ unsigned enc_f(float f) {
    unsigned u = __float_as_uint(f);
    return (u & 0x80000000u) ? ~u : (u | 0x80000000u);
}
__device__ __forceinline__ float dec_f(unsigned u) {
    return (u & 0x80000000u) ? __uint_as_float(u & 0x7FFFFFFFu) : __uint_as_float(~u);
}

__device__ __forceinline__ float bflo(unsigned u) { return __uint_as_float(u << 16); }
__device__ __forceinline__ float bfhi(unsigned u) { return __uint_as_float(u & 0xFFFF0000u); }

// ---- Kernel P3: proj[r][n][k] = emb[n] @ W_R[r] ----
// Register-budget-safe design: each lane holds only HALF a W column (32 floats)
// -> ~45 live VGPRs, under the observed 64-VGPR allocator cap that made both
// previous proj kernels spill to scratch (15 GB / 4.5 GB phantom HBM traffic).
// Wave layout: lane = (h, c): c = lane&31 -> column within half, h = lane>>5
// -> d-half. Wave covers 32 cols; q = wave&1 picks col half; p = wave>>1 picks
// 16-node subset. One __shfl_xor(32) combines the two d-halves.
__global__ void __launch_bounds__(256)
k_proj3(const float* __restrict__ emb, const float* __restrict__ WR,
        unsigned short* __restrict__ proj)
{
    int t = threadIdx.x;
    int wv = t >> 6;
    int lane = t & 63;
    int c = lane & 31;
    int h = lane >> 5;
    int q = wv & 1;
    int p = wv >> 1;
    int r = blockIdx.y;
    int col = q * 32 + c;
    const float* __restrict__ Wr = WR + ((long)r * DD + h * 32) * DDR + col;
    float w[32];
#pragma unroll
    for (int d = 0; d < 32; ++d) w[d] = Wr[d * DDR];   // coalesced, once per wave
    int nbase = blockIdx.x * 32 + p * 16;
    int nend = (nbase + 16 < NN) ? (nbase + 16) : NN;
    for (int n = nbase; n < nend; ++n) {
        const float* __restrict__ x = emb + (long)n * DD + h * 32;
        float acc = 0.f;
#pragma unroll
        for (int d4 = 0; d4 < 8; ++d4) {
            float4 xv = *(const float4*)(x + d4 * 4);   // 2 bcast addrs per wave
            acc = fmaf(xv.x, w[d4 * 4 + 0], acc);
            acc = fmaf(xv.y, w[d4 * 4 + 1], acc);
            acc = fmaf(xv.z, w[d4 * 4 + 2], acc);
            acc = fmaf(xv.w, w[d4 * 4 + 3], acc);
        }
        acc += __shfl_xor(acc, 32);                     // combine d-halves
        if (h == 0) {
            __hip_bfloat16 hb = __float2bfloat16(acc);
            proj[((long)r * NN + n) * DDR + col] = *reinterpret_cast<unsigned short*>(&hb);
        }
    }
}

// ---- Kernel A': gather attention logits + segment max (16 lanes/edge) ----
__global__ void k_attg(const unsigned* __restrict__ proj, const float* __restrict__ rel,
                       const int* __restrict__ src, const int* __restrict__ dst,
                       const int* __restrict__ et,
                       float* __restrict__ att, unsigned* __restrict__ mkey)
{
    long tid = (long)blockIdx.x * blockDim.x + threadIdx.x;
    int e = (int)(tid >> 4);
    int j = threadIdx.x & 15;
    if (e >= NE) return;
    int s = src[e], d = dst[e], r = et[e];
    uint2 tv = *(const uint2*)(proj + ((long)r * NN + s) * 32 + j * 2);
    uint2 hv = *(const uint2*)(proj + ((long)r * NN + d) * 32 + j * 2);
    float4 rv = *(const float4*)(rel + r * DDR + j * 4);
    float sum = bflo(tv.x) * tanhf(bflo(hv.x) + rv.x)
              + bfhi(tv.x) * tanhf(bfhi(hv.x) + rv.y)
              + bflo(tv.y) * tanhf(bflo(hv.y) + rv.z)
              + bfhi(tv.y) * tanhf(bfhi(hv.y) + rv.w);
#pragma unroll
    for (int off = 8; off; off >>= 1) sum += __shfl_xor(sum, off);
    if (j == 0) {
        att[e] = sum;
        atomicMax(mkey + d, enc_f(sum));
    }
}

// ---- Fallback kernel (old direct per-edge matvec) if ws too small ----
__global__ void k_att(const float* __restrict__ emb, const float* __restrict__ rel,
                      const float* __restrict__ WR, const int* __restrict__ src,
                      const int* __restrict__ dst, const int* __restrict__ et,
                      float* __restrict__ att, unsigned* __restrict__ mkey)
{
    int e = (int)((blockIdx.x * blockDim.x + threadIdx.x) >> 6);
    int lane = threadIdx.x & 63;
    if (e >= NE) return;
    int s = src[e], d = dst[e], r = et[e];
    const float* __restrict__ es = emb + (long)s * DD;
    const float* __restrict__ eh = emb + (long)d * DD;
    const float* __restrict__ w  = WR + r * (DD * DDR) + lane;
    float at = 0.f, ah = 0.f;
#pragma unroll 8
    for (int dd = 0; dd < DD; ++dd) {
        float ws = w[dd * DDR];
        at = fmaf(es[dd], ws, at);
        ah = fmaf(eh[dd], ws, ah);
    }
    float term = at * tanhf(ah + rel[r * DDR + lane]);
#pragma unroll
    for (int off = 32; off; off >>= 1) term += __shfl_xor(term, off);
    if (lane == 0) {
        att[e] = term;
        atomicMax(mkey + d, enc_f(term));
    }
}

// ---- Kernel B: ex = exp(att - m[dst]); segment sum ----
__global__ void k_expsum(const int* __restrict__ dst, float* __restrict__ att,
                         const unsigned* __restrict__ mkey, float* __restrict__ ssum)
{
    int e = blockIdx.x * blockDim.x + threadIdx.x;
    if (e >= NE) return;
    int d = dst[e];
    float ex = expf(att[e] - dec_f(mkey[d]));
    att[e] = ex;
    atomicAdd(ssum + d, ex);
}

// ---- Kernel D: layer-0 aggregation; finalizes a[e] = ex/ssum ----
__global__ void k_agg0(const float* __restrict__ emb, const int* __restrict__ src,
                       const int* __restrict__ dst, float* __restrict__ att,
                       const float* __restrict__ ssum, float* __restrict__ Nh)
{
    int e = (int)((blockIdx.x * blockDim.x + threadIdx.x) >> 6);
    int lane = threadIdx.x & 63;
    if (e >= NE) return;
    int s = src[e], d = dst[e];
    float a = att[e] / ssum[d];
    if (lane == 0) att[e] = a;
    float v = emb[(long)s * DD + lane] * a;
    atomicAdd(Nh + (long)d * DD + lane, v);
}

// ---- Kernel E: layer-0 node update; writes ego (cols 0..64) and h1 (cols 64..96) ----
__global__ void k_node0(const float* __restrict__ emb, const float* __restrict__ Nh,
                        const float* __restrict__ W1, const float* __restrict__ b1,
                        const float* __restrict__ W2, const float* __restrict__ b2,
                        float* __restrict__ out)
{
    int node = (int)((blockIdx.x * blockDim.x + threadIdx.x) >> 6);
    int lane = threadIdx.x & 63;
    if (node >= NN) return;
    const float* __restrict__ x  = emb + (long)node * DD;
    const float* __restrict__ nh = Nh + (long)node * DD;
    int j = lane & 31;
    const float* __restrict__ W = (lane < 32) ? (W1 + j * DD) : (W2 + j * DD);
    float acc = 0.f;
#pragma unroll 8
    for (int dd = 0; dd < DD; ++dd) {
        float xv = x[dd], nv = nh[dd];
        float v = (lane < 32) ? (xv + nv) : (xv * nv);
        acc = fmaf(v, W[dd], acc);
    }
    acc += (lane < 32) ? b1[j] : b2[j];
    acc = (acc >= 0.f) ? acc : 0.01f * acc;
    float other = __shfl_down(acc, 32);
    float h = acc + other;
    float ss = h * h;
#pragma unroll
    for (int off = 16; off; off >>= 1) ss += __shfl_xor(ss, off);
    float nrm = sqrtf(ss);
    float hn = h / fmaxf(nrm, 1e-12f);
    out[(long)node * 112 + lane] = x[lane];
    if (lane < 32) out[(long)node * 112 + 64 + j] = hn;
}

// ---- Kernel F: layer-1 aggregation ----
__global__ void k_agg1(const float* __restrict__ out, const int* __restrict__ src,
                       const int* __restrict__ dst, const float* __restrict__ att,
                       float* __restrict__ Nh1)
{
    int idx = blockIdx.x * blockDim.x + threadIdx.x;
    int e = idx >> 5;
    int j = idx & 31;
    if (e >= NE) return;
    int s = src[e], d = dst[e];
    float a = att[e];
    float v = out[(long)s * 112 + 64 + j] * a;
    atomicAdd(Nh1 + (long)d * 32 + j, v);
}

// ---- Kernel G: layer-1 node update; writes h2 (cols 96..112) ----
__global__ void k_node1(const float* __restrict__ outbuf, const float* __restrict__ Nh1,
                        const float* __restrict__ W1, const float* __restrict__ b1,
                        const float* __restrict__ W2, const float* __restrict__ b2,
                        float* __restrict__ out)
{
    int t = blockIdx.x * blockDim.x + threadIdx.x;
    int node = t >> 5;
    int lane = t & 31;
    if (node >= NN) return;
    const float* __restrict__ x  = outbuf + (long)node * 112 + 64;
    const float* __restrict__ nh = Nh1 + (long)node * 32;
    int j = lane & 15;
    const float* __restrict__ W = (lane < 16) ? (W1 + j * 32) : (W2 + j * 32);
    float acc = 0.f;
#pragma unroll 8
    for (int dd = 0; dd < 32; ++dd) {
        float xv = x[dd], nv = nh[dd];
        float v = (lane < 16) ? (xv + nv) : (xv * nv);
        acc = fmaf(v, W[dd], acc);
    }
    acc += (lane < 16) ? b1[j] : b2[j];
    acc = (acc >= 0.f) ? acc : 0.01f * acc;
    float other = __shfl_down(acc, 16, 32);
    float h = acc + other;
    float ss = h * h;
#pragma unroll
    for (int off = 8; off; off >>= 1) ss += __shfl_xor(ss, off);
    float nrm = sqrtf(ss);
    float hn = h / fmaxf(nrm, 1e-12f);
    if (lane < 16) out[(long)node * 112 + 96 + j] = hn;
}

extern "C" void kernel_launch(void* const* d_in, const int* in_sizes, int n_in,
                              void* d_out, int out_size, void* d_ws, size_t ws_size,
                              hipStream_t stream) {
    const float* emb  = (const float*)d_in[0];
    const float* rel  = (const float*)d_in[1];
    const float* WR   = (const float*)d_in[2];
    const float* W1_0 = (const float*)d_in[3];
    const float* b1_0 = (const float*)d_in[4];
    const float* W2_0 = (const float*)d_in[5];
    const float* b2_0 = (const float*)d_in[6];
    const float* W1_1 = (const float*)d_in[7];
    const float* b1_1 = (const float*)d_in[8];
    const float* W2_1 = (const float*)d_in[9];
    const float* b2_1 = (const float*)d_in[10];
    const int*   src  = (const int*)d_in[11];
    const int*   dst  = (const int*)d_in[12];
    const int*   et   = (const int*)d_in[13];
    float* out = (float*)d_out;

    // workspace layout (floats): [mkey N][ssum N][Nh0 64N][Nh1 32N][att E][proj bf16 N*R*64]
    unsigned* mkey = (unsigned*)d_ws;
    float* ssum = (float*)d_ws + NN;
    float* Nh0  = (float*)d_ws + 2 * NN;
    float* Nh1  = (float*)d_ws + (2 + DD) * NN;
    float* att  = (float*)d_ws + (2 + DD + 32) * NN;
    unsigned* proj = (unsigned*)(att + NE);

    size_t need = (size_t)(2 + DD + 32) * NN * 4 + (size_t)NE * 4
                + (size_t)NN * NR * DDR * 2;

    // zero mkey/ssum/Nh0/Nh1 (att & proj fully overwritten)
    hipMemsetAsync(d_ws, 0, (size_t)(2 + DD + 32) * NN * sizeof(float), stream);

    if (ws_size >= need) {
        k_proj3<<<dim3((NN + 31) / 32, NR), dim3(256), 0, stream>>>(
            emb, WR, (unsigned short*)proj);
        k_attg<<<dim3((int)(((long)NE * 16 + 255) / 256)), dim3(256), 0, stream>>>(
            proj, rel, src, dst, et, att, mkey);
    } else {
        k_att<<<dim3((int)(((long)NE * 64 + 255) / 256)), dim3(256), 0, stream>>>(
            emb, rel, WR, src, dst, et, att, mkey);
    }
    k_expsum<<<dim3((NE + 255) / 256), dim3(256), 0, stream>>>(dst, att, mkey, ssum);
    k_agg0<<<dim3((int)(((long)NE * 64 + 255) / 256)), dim3(256), 0, stream>>>(
        emb, src, dst, att, ssum, Nh0);
    k_node0<<<dim3((int)(((long)NN * 64 + 255) / 256)), dim3(256), 0, stream>>>(
        emb, Nh0, W1_0, b1_0, W2_0, b2_0, out);
    k_agg1<<<dim3((int)(((long)NE * 32 + 255) / 256)), dim3(256), 0, stream>>>(
        out, src, dst, att, Nh1);
    k_node1<<<dim3((int)(((long)NN * 32 + 255) / 256)), dim3(256), 0, stream>>>(
        out, Nh1, W1_1, b1_1, W2_1, b2_1, out);
}